// Round 1
// baseline (1797.531 us; speedup 1.0000x reference)
//
#include <hip/hip_runtime.h>

#define BB 4
#define VV 256
#define HH 128
#define NROWS (BB*VV)            // 1024
#define NE_CNT (BB*VV*VV)        // 262144
#define EPSV 1e-5f

typedef float4 f4;

__device__ __forceinline__ float sigm(float x) {
    return 1.f / (1.f + __expf(-x));
}

#define COMP(v,kk) ((kk)==0 ? (v).x : (kk)==1 ? (v).y : (kk)==2 ? (v).z : (v).w)

// ---------------------------------------------------------------------------
// K1: Uh/Vh/Ah/Bh = h @ W{U,V,A,B}^T + b   (1024 x 128, K=128)
// ---------------------------------------------------------------------------
__global__ __launch_bounds__(256) void k_linear4(
    const float* __restrict__ h,
    const float* __restrict__ W0, const float* __restrict__ b0,
    const float* __restrict__ W1, const float* __restrict__ b1,
    const float* __restrict__ W2, const float* __restrict__ b2,
    const float* __restrict__ W3, const float* __restrict__ b3,
    float* __restrict__ out)
{
    __shared__ float hs[4*HH];
    const int tid = threadIdx.x;
    const int r0  = blockIdx.x * 4;
    if (tid < 128) {
        int r = tid >> 5, kq = (tid & 31) << 2;
        *(f4*)&hs[r*HH + kq] = *(const f4*)&h[(r0 + r)*HH + kq];
    }
    __syncthreads();
    const int n  = tid & 127;
    const int s0 = tid >> 7;                       // 0 or 1
    const float* Ws[4] = {W0, W1, W2, W3};
    const float* bs[4] = {b0, b1, b2, b3};
    for (int ss = 0; ss < 2; ++ss) {
        const int sel = s0 + ss*2;
        const float* wrow = Ws[sel] + n*HH;
        float a0=0.f, a1=0.f, a2=0.f, a3=0.f;
        for (int kq = 0; kq < 32; ++kq) {
            f4 w = *(const f4*)&wrow[kq<<2];
            float wq[4] = {w.x, w.y, w.z, w.w};
            #pragma unroll
            for (int q = 0; q < 4; ++q) {
                int k = (kq<<2) + q;
                float wv = wq[q];
                a0 += hs[0*HH + k] * wv;
                a1 += hs[1*HH + k] * wv;
                a2 += hs[2*HH + k] * wv;
                a3 += hs[3*HH + k] * wv;
            }
        }
        float bias = bs[sel][n];
        float* o = out + sel*(NROWS*HH);
        o[(r0+0)*HH + n] = a0 + bias;
        o[(r0+1)*HH + n] = a1 + bias;
        o[(r0+2)*HH + n] = a2 + bias;
        o[(r0+3)*HH + n] = a3 + bias;
    }
}

// ---------------------------------------------------------------------------
// K1b: WCt[k][n] = WC[n][k]  (128x128, LDS-tiled transpose)
// ---------------------------------------------------------------------------
__global__ __launch_bounds__(256) void k_transpose(
    const float* __restrict__ in, float* __restrict__ out)
{
    __shared__ float t[32][33];
    int ti = blockIdx.x >> 2, tj = blockIdx.x & 3;
    int tx = threadIdx.x & 31, ty = threadIdx.x >> 5;   // ty 0..7
    for (int yy = ty; yy < 32; yy += 8)
        t[yy][tx] = in[(ti*32 + yy)*HH + tj*32 + tx];
    __syncthreads();
    for (int yy = ty; yy < 32; yy += 8)
        out[(tj*32 + yy)*HH + ti*32 + tx] = t[tx][yy];
}

// ---------------------------------------------------------------------------
// K2 v3: per (b,i): Ce GEMM (256j x 128n, K=128) fused with e_new epilogue.
//
// Pipeline rewrite vs v2 (which was latency-bound: VALUBusy 31%, HBM 17%,
// staging fully exposed between 2 barriers/chunk at 8 waves/CU):
//  - 512 threads, thread tile 8j x 8n (acc 64 VGPR).
//  - K-chunk 16; es/wc DOUBLE-buffered in LDS (2x16KB + 2x8KB = 48KB+2KB).
//  - Register-staged prefetch: global loads for chunk kc+1 issue right after
//    the single barrier of chunk kc; they land during ~2000cy of FMA, so the
//    ds_write at top of kc+1 never waits on HBM (T14 async-split, T3 2-phase).
//  - ONE barrier per chunk: ds_write(buf[kc&1]) races only with compute(kc-2),
//    which is fenced by the barrier of kc-1.
//  - es slot-XOR swizzle (s ^= j&3, applied on BOTH write and read) makes the
//    stride-16 row layout conflict-free on ds_read_b128 (2-way max = free).
//  - __launch_bounds__(512,4) caps VGPR at 128 -> 2 blocks/CU = 16 waves/CU.
// ---------------------------------------------------------------------------
__global__ __launch_bounds__(512, 4) void k_edge(
    const float* __restrict__ e, const int* __restrict__ A, const int* __restrict__ S,
    const float* __restrict__ WCt, const float* __restrict__ bC,
    const float* __restrict__ Ahw, const float* __restrict__ Bhw,
    const float* __restrict__ Vhw,
    float* __restrict__ eout, float* __restrict__ aggS, float* __restrict__ aggA,
    float* __restrict__ sums)
{
    __shared__ float es[2][4096];        // 2 x 16 KB: 256 j x 16 k, slot-swizzled
    __shared__ float wc[2][2048];        // 2 x 8 KB : 16 k x 128 n, linear
    __shared__ float s_aggS[HH], s_aggA[HH], s_sum[HH], s_ssq[HH];

    const int t  = threadIdx.x;
    const int bi = blockIdx.x;           // b*V + i
    const int b  = bi >> 8;
    if (t < HH) { s_aggS[t]=0.f; s_aggA[t]=0.f; s_sum[t]=0.f; s_ssq[t]=0.f; }

    const int tn  = t & 15;              // n = tn*4 + qq + q*64
    const int tjg = t >> 4;              // j = tjg + jj*32   (tjg 0..31)

    float acc[8][8];
    #pragma unroll
    for (int jj = 0; jj < 8; ++jj)
        #pragma unroll
        for (int q = 0; q < 8; ++q) acc[jj][q] = 0.f;

    const f4* e4   = (const f4*)e;
    const f4* wct4 = (const f4*)WCt;

    // Staging sources. es slot idx = m*512 + t -> row j = idx>>2, slot s = idx&3.
    // Global slot fetched for LDS slot (j,s) is s ^ (j&3)  (read applies same XOR).
    const int j0 = t >> 2;                       // row for m=0 (m=1 adds 128; j&3 same)
    const int sp = (t & 3) ^ (j0 & 3);
    const f4* p_es0 = e4 + (size_t)(bi*VV + j0)*32 + sp;
    const f4* p_es1 = p_es0 + (size_t)128*32;
    const f4* p_wc  = wct4 + t;                  // k = t>>5, n4 = t&31 (linear)

    f4 r0 = p_es0[0];                            // prologue: chunk 0
    f4 r1 = p_es1[0];
    f4 rw = p_wc[0];

    #pragma unroll 2
    for (int kc = 0; kc < 8; ++kc) {
        float* esb = es[kc & 1];
        float* wcb = wc[kc & 1];
        *(f4*)&esb[t*4]        = r0;             // waits vmcnt for own loads only
        *(f4*)&esb[2048 + t*4] = r1;
        *(f4*)&wcb[t*4]        = rw;
        __syncthreads();                         // single barrier per chunk
        if (kc < 7) {                            // prefetch chunk kc+1 into regs;
            r0 = p_es0[(kc+1)*4];                // completes under the FMA below
            r1 = p_es1[(kc+1)*4];
            rw = p_wc[(kc+1)*512];
        }
        #pragma unroll
        for (int kq = 0; kq < 4; ++kq) {         // 4-k groups within the 16-chunk
            const int sw = ((kq ^ (tjg & 3)) << 2);   // XOR-swizzled slot (floats)
            #pragma unroll
            for (int jh = 0; jh < 2; ++jh) {     // split jj to cap live aj regs
                f4 a0 = *(const f4*)&esb[(tjg + (jh*4+0)*32)*16 + sw];
                f4 a1 = *(const f4*)&esb[(tjg + (jh*4+1)*32)*16 + sw];
                f4 a2 = *(const f4*)&esb[(tjg + (jh*4+2)*32)*16 + sw];
                f4 a3 = *(const f4*)&esb[(tjg + (jh*4+3)*32)*16 + sw];
                #pragma unroll
                for (int kk = 0; kk < 4; ++kk) {
                    const float* wrow = &wcb[(kq*4 + kk)*128 + tn*4];
                    f4 w0 = *(const f4*)&wrow[0];
                    f4 w1 = *(const f4*)&wrow[64];
                    float v0 = COMP(a0,kk), v1 = COMP(a1,kk);
                    float v2 = COMP(a2,kk), v3 = COMP(a3,kk);
                    #pragma unroll
                    for (int jl = 0; jl < 4; ++jl) {
                        float a = (jl==0)?v0:(jl==1)?v1:(jl==2)?v2:v3;
                        float* ac = acc[jh*4 + jl];
                        ac[0] += a*w0.x; ac[1] += a*w0.y;
                        ac[2] += a*w0.z; ac[3] += a*w0.w;
                        ac[4] += a*w1.x; ac[5] += a*w1.y;
                        ac[6] += a*w1.z; ac[7] += a*w1.w;
                    }
                }
            }
        }
    }

    // ---- epilogue: e_new = acc + bC + Bh[i] + Ah[j]; store; stats; aggs ----
    float bcv[8], bhv[8];
    #pragma unroll
    for (int q = 0; q < 2; ++q) {
        f4 bc4 = *(const f4*)&bC[tn*4 + q*64];
        f4 bh4 = *(const f4*)&Bhw[bi*HH + tn*4 + q*64];
        bcv[q*4+0]=bc4.x; bcv[q*4+1]=bc4.y; bcv[q*4+2]=bc4.z; bcv[q*4+3]=bc4.w;
        bhv[q*4+0]=bh4.x; bhv[q*4+1]=bh4.y; bhv[q*4+2]=bh4.z; bhv[q*4+3]=bh4.w;
    }
    float sm[8], sq[8], aS[8], aA[8];
    #pragma unroll
    for (int q = 0; q < 8; ++q) { sm[q]=0.f; sq[q]=0.f; aS[q]=0.f; aA[q]=0.f; }

    const int* Sp = S + bi*VV;
    const int* Ap = A + bi*VV;
    #pragma unroll
    for (int jj = 0; jj < 8; ++jj) {
        const int j = tjg + jj*32;
        const float* ahp = &Ahw[(size_t)(b*VV + j)*HH];
        const float* vhp = &Vhw[(size_t)(b*VV + j)*HH];
        const int Sij = Sp[j], Aij = Ap[j];
        #pragma unroll
        for (int q = 0; q < 2; ++q) {
            f4 ah = *(const f4*)&ahp[tn*4 + q*64];
            f4 vh = *(const f4*)&vhp[tn*4 + q*64];
            f4 env;
            env.x = acc[jj][q*4+0] + bcv[q*4+0] + bhv[q*4+0] + ah.x;
            env.y = acc[jj][q*4+1] + bcv[q*4+1] + bhv[q*4+1] + ah.y;
            env.z = acc[jj][q*4+2] + bcv[q*4+2] + bhv[q*4+2] + ah.z;
            env.w = acc[jj][q*4+3] + bcv[q*4+3] + bhv[q*4+3] + ah.w;
            *(f4*)&eout[((size_t)(bi*VV) + j)*HH + tn*4 + q*64] = env;
            float vv[4] = {vh.x, vh.y, vh.z, vh.w};
            float ev[4] = {env.x, env.y, env.z, env.w};
            #pragma unroll
            for (int qq = 0; qq < 4; ++qq) {
                float v = ev[qq];
                sm[q*4+qq] += v;
                sq[q*4+qq] += v*v;
                if (!Aij) aA[q*4+qq] += vv[qq];
                if (!Sij) aS[q*4+qq] += vv[qq] * sigm(v);
            }
        }
    }
    #pragma unroll
    for (int q = 0; q < 2; ++q)
        #pragma unroll
        for (int qq = 0; qq < 4; ++qq) {
            int n = tn*4 + q*64 + qq;
            atomicAdd(&s_sum[n],  sm[q*4+qq]);
            atomicAdd(&s_ssq[n],  sq[q*4+qq]);
            atomicAdd(&s_aggS[n], aS[q*4+qq]);
            atomicAdd(&s_aggA[n], aA[q*4+qq]);
        }
    __syncthreads();
    if (t < HH) {
        aggS[bi*HH + t] = s_aggS[t];
        aggA[bi*HH + t] = s_aggA[t];
        atomicAdd(&sums[t],      s_sum[t]);   // e channel sum
        atomicAdd(&sums[HH + t], s_ssq[t]);   // e channel sumsq
    }
}

// ---------------------------------------------------------------------------
// K3a: h_new = Uh + aggS + aggA ; accumulate h channel sums
// ---------------------------------------------------------------------------
__global__ __launch_bounds__(256) void k_hnew(
    const float* __restrict__ Uh, const float* __restrict__ aggS,
    const float* __restrict__ aggA, float* __restrict__ h_new,
    float* __restrict__ sums)
{
    __shared__ float ssm[HH], ssq[HH];
    const int tid = threadIdx.x;
    if (tid < 128) { ssm[tid]=0.f; ssq[tid]=0.f; }
    __syncthreads();
    int gid = blockIdx.x*256 + tid;
    f4 u = *(const f4*)&Uh[gid*4];
    f4 s = *(const f4*)&aggS[gid*4];
    f4 a = *(const f4*)&aggA[gid*4];
    float v0=u.x+s.x+a.x, v1=u.y+s.y+a.y, v2=u.z+s.z+a.z, v3=u.w+s.w+a.w;
    *(f4*)&h_new[gid*4] = make_float4(v0,v1,v2,v3);
    int n0 = (gid*4) & 127;
    atomicAdd(&ssm[n0+0], v0); atomicAdd(&ssq[n0+0], v0*v0);
    atomicAdd(&ssm[n0+1], v1); atomicAdd(&ssq[n0+1], v1*v1);
    atomicAdd(&ssm[n0+2], v2); atomicAdd(&ssq[n0+2], v2*v2);
    atomicAdd(&ssm[n0+3], v3); atomicAdd(&ssq[n0+3], v3*v3);
    __syncthreads();
    if (tid < 128) {
        atomicAdd(&sums[256 + tid], ssm[tid]);
        atomicAdd(&sums[384 + tid], ssq[tid]);
    }
}

// ---------------------------------------------------------------------------
// K3b: finalize batchnorm params -> scale/shift per channel
// ---------------------------------------------------------------------------
__global__ void k_stats(const float* __restrict__ sums, float* __restrict__ outs,
                        const float* __restrict__ gamma_e, const float* __restrict__ beta_e,
                        const float* __restrict__ gamma_h, const float* __restrict__ beta_h)
{
    int n = threadIdx.x;   // 128
    float em  = sums[n] * (1.f/(float)NE_CNT);
    float ev  = sums[128+n] * (1.f/(float)NE_CNT) - em*em;
    float esc = rsqrtf(ev + EPSV) * gamma_e[n];
    outs[n]       = esc;
    outs[128 + n] = beta_e[n] - em*esc;
    float hm  = sums[256+n] * (1.f/1024.f);
    float hv  = sums[384+n] * (1.f/1024.f) - hm*hm;
    float hsc = rsqrtf(hv + EPSV) * gamma_h[n];
    outs[256 + n] = hsc;
    outs[384 + n] = beta_h[n] - hm*hsc;
}

// ---------------------------------------------------------------------------
// K4h: h_out = h_in + relu(bn(h_new))
// ---------------------------------------------------------------------------
__global__ __launch_bounds__(256) void k_hout(
    const float* __restrict__ h_in, const float* __restrict__ h_new,
    const float* __restrict__ outs, float* __restrict__ hout)
{
    int gid = blockIdx.x*256 + threadIdx.x;
    int n0 = (gid*4) & 127;
    f4 x  = *(const f4*)&h_new[gid*4];
    f4 hi = *(const f4*)&h_in[gid*4];
    f4 sc = *(const f4*)&outs[256 + n0];
    f4 sh = *(const f4*)&outs[384 + n0];
    f4 y;
    y.x = fmaxf(x.x*sc.x + sh.x, 0.f) + hi.x;
    y.y = fmaxf(x.y*sc.y + sh.y, 0.f) + hi.y;
    y.z = fmaxf(x.z*sc.z + sh.z, 0.f) + hi.z;
    y.w = fmaxf(x.w*sc.w + sh.w, 0.f) + hi.w;
    *(f4*)&hout[gid*4] = y;
}

// ---------------------------------------------------------------------------
// K4e: e_out = e_in + relu(bn(e_new))   (e_new lives in-place in d_out)
// ---------------------------------------------------------------------------
__global__ __launch_bounds__(256) void k_eout(
    const float* __restrict__ e_in, const float* __restrict__ outs,
    float* __restrict__ eio)
{
    size_t gid = (size_t)blockIdx.x*256 + threadIdx.x;
    int n0 = ((int)(gid & 31)) << 2;
    f4 x  = *(const f4*)&eio[gid*4];
    f4 ei = *(const f4*)&e_in[gid*4];
    f4 sc = *(const f4*)&outs[n0];
    f4 sh = *(const f4*)&outs[128 + n0];
    f4 y;
    y.x = fmaxf(x.x*sc.x + sh.x, 0.f) + ei.x;
    y.y = fmaxf(x.y*sc.y + sh.y, 0.f) + ei.y;
    y.z = fmaxf(x.z*sc.z + sh.z, 0.f) + ei.z;
    y.w = fmaxf(x.w*sc.w + sh.w, 0.f) + ei.w;
    *(f4*)&eio[gid*4] = y;
}

// ---------------------------------------------------------------------------
extern "C" void kernel_launch(void* const* d_in, const int* in_sizes, int n_in,
                              void* d_out, int out_size, void* d_ws, size_t ws_size,
                              hipStream_t stream)
{
    (void)in_sizes; (void)n_in; (void)out_size; (void)ws_size;
    const float* h   = (const float*)d_in[0];
    const float* e   = (const float*)d_in[1];
    const int*   A   = (const int*)d_in[2];
    const int*   S   = (const int*)d_in[3];
    const float* WU  = (const float*)d_in[4];   const float* bU = (const float*)d_in[5];
    const float* WV  = (const float*)d_in[6];   const float* bV = (const float*)d_in[7];
    const float* WA_ = (const float*)d_in[8];   const float* bA = (const float*)d_in[9];
    const float* WB_ = (const float*)d_in[10];  const float* bB = (const float*)d_in[11];
    const float* WC_ = (const float*)d_in[12];  const float* bC = (const float*)d_in[13];
    const float* gamma_h = (const float*)d_in[14]; const float* beta_h = (const float*)d_in[15];
    const float* gamma_e = (const float*)d_in[16]; const float* beta_e = (const float*)d_in[17];

    float* ws    = (float*)d_ws;
    float* Uh    = ws;              // 1024*128
    float* Vh    = ws + 131072;
    float* Ahw   = ws + 262144;
    float* Bhw   = ws + 393216;
    float* aggS  = ws + 524288;
    float* aggA  = ws + 655360;
    float* h_new = ws + 786432;
    float* WCt   = ws + 917504;     // 128*128
    float* sums  = ws + 933888;     // 512: e_sum, e_ssq, h_sum, h_ssq
    float* outs  = ws + 934400;     // 512: e_scale, e_shift, h_scale, h_shift

    float* hout = (float*)d_out;
    float* eout = (float*)d_out + NROWS*HH;     // e_new then e_out, in place

    hipMemsetAsync(sums, 0, 512*sizeof(float), stream);
    k_linear4 <<<256,   256, 0, stream>>>(h, WU,bU, WV,bV, WA_,bA, WB_,bB, Uh);
    k_transpose<<<16,   256, 0, stream>>>(WC_, WCt);
    k_edge    <<<1024,  512, 0, stream>>>(e, A, S, WCt, bC, Ahw, Bhw, Vh,
                                          eout, aggS, aggA, sums);
    k_hnew    <<<128,   256, 0, stream>>>(Uh, aggS, aggA, h_new, sums);
    k_stats   <<<1,     128, 0, stream>>>(sums, outs, gamma_e, beta_e, gamma_h, beta_h);
    k_hout    <<<128,   256, 0, stream>>>(h, h_new, outs, hout);
    k_eout    <<<32768, 256, 0, stream>>>(e, outs, eout);
}

// Round 3
// 1288.740 us; speedup vs baseline: 1.3948x; 1.3948x over previous
//
#include <hip/hip_runtime.h>

#define BB 4
#define VV 256
#define HH 128
#define NROWS (BB*VV)            // 1024
#define NE_CNT (BB*VV*VV)        // 262144
#define EPSV 1e-5f

typedef float4 f4;

__device__ __forceinline__ float sigm(float x) {
    return 1.f / (1.f + __expf(-x));
}

#define COMP(v,kk) ((kk)==0 ? (v).x : (kk)==1 ? (v).y : (kk)==2 ? (v).z : (v).w)

// ---------------------------------------------------------------------------
// K1: Uh/Vh/Ah/Bh = h @ W{U,V,A,B}^T + b   (1024 x 128, K=128)
// ---------------------------------------------------------------------------
__global__ __launch_bounds__(256) void k_linear4(
    const float* __restrict__ h,
    const float* __restrict__ W0, const float* __restrict__ b0,
    const float* __restrict__ W1, const float* __restrict__ b1,
    const float* __restrict__ W2, const float* __restrict__ b2,
    const float* __restrict__ W3, const float* __restrict__ b3,
    float* __restrict__ out)
{
    __shared__ float hs[4*HH];
    const int tid = threadIdx.x;
    const int r0  = blockIdx.x * 4;
    if (tid < 128) {
        int r = tid >> 5, kq = (tid & 31) << 2;
        *(f4*)&hs[r*HH + kq] = *(const f4*)&h[(r0 + r)*HH + kq];
    }
    __syncthreads();
    const int n  = tid & 127;
    const int s0 = tid >> 7;                       // 0 or 1
    const float* Ws[4] = {W0, W1, W2, W3};
    const float* bs[4] = {b0, b1, b2, b3};
    for (int ss = 0; ss < 2; ++ss) {
        const int sel = s0 + ss*2;
        const float* wrow = Ws[sel] + n*HH;
        float a0=0.f, a1=0.f, a2=0.f, a3=0.f;
        for (int kq = 0; kq < 32; ++kq) {
            f4 w = *(const f4*)&wrow[kq<<2];
            float wq[4] = {w.x, w.y, w.z, w.w};
            #pragma unroll
            for (int q = 0; q < 4; ++q) {
                int k = (kq<<2) + q;
                float wv = wq[q];
                a0 += hs[0*HH + k] * wv;
                a1 += hs[1*HH + k] * wv;
                a2 += hs[2*HH + k] * wv;
                a3 += hs[3*HH + k] * wv;
            }
        }
        float bias = bs[sel][n];
        float* o = out + sel*(NROWS*HH);
        o[(r0+0)*HH + n] = a0 + bias;
        o[(r0+1)*HH + n] = a1 + bias;
        o[(r0+2)*HH + n] = a2 + bias;
        o[(r0+3)*HH + n] = a3 + bias;
    }
}

// ---------------------------------------------------------------------------
// K1b: WCt[k][n] = WC[n][k]  (128x128, LDS-tiled transpose)
// ---------------------------------------------------------------------------
__global__ __launch_bounds__(256) void k_transpose(
    const float* __restrict__ in, float* __restrict__ out)
{
    __shared__ float t[32][33];
    int ti = blockIdx.x >> 2, tj = blockIdx.x & 3;
    int tx = threadIdx.x & 31, ty = threadIdx.x >> 5;   // ty 0..7
    for (int yy = ty; yy < 32; yy += 8)
        t[yy][tx] = in[(ti*32 + yy)*HH + tj*32 + tx];
    __syncthreads();
    for (int yy = ty; yy < 32; yy += 8)
        out[(tj*32 + yy)*HH + ti*32 + tx] = t[tx][yy];
}

// ---------------------------------------------------------------------------
// K2 v4: per block: half-row Ce GEMM (128j x 128n, K=128) + e_new epilogue.
//
// v3 post-mortem: __launch_bounds__(512,4) capped VGPR at 128 -> compiler
// picked the 64-reg bin and spilled everything (FETCH 1.7GB, VALUBusy 5%).
// Fix: keep the dbuf+reg-prefetch pipeline but fit the register budget:
//  - 256 threads, block tile 128j x 128n (grid 2048: bi x jhalf).
//  - per-thread 8j x 8n (acc=64) -> ~150 live VGPR incl. epilogue stats.
//  - __launch_bounds__(256,3): 3 waves/SIMD, VGPR cap ~170 -> NO spill,
//    12 waves/CU (vs v2's 7) with pipelined staging.
//  - K-chunk 16, es/wc double-buffered (16+16 KB), ONE barrier per chunk;
//    global loads for chunk kc+1 issue right after the barrier of kc and
//    complete under ~512 cyc of FMA (T14 async-split).
//  - es slot-XOR swizzle (s ^ j&3 on both write & read): conflict-free
//    ds_read_b128 at row stride 16 floats.
//  - j-split => aggS/aggA accumulated via atomicAdd (memset beforehand).
// ---------------------------------------------------------------------------
__global__ __launch_bounds__(256, 3) void k_edge(
    const float* __restrict__ e, const int* __restrict__ A, const int* __restrict__ S,
    const float* __restrict__ WCt, const float* __restrict__ bC,
    const float* __restrict__ Ahw, const float* __restrict__ Bhw,
    const float* __restrict__ Vhw,
    float* __restrict__ eout, float* __restrict__ aggS, float* __restrict__ aggA,
    float* __restrict__ sums)
{
    __shared__ float es[2][2048];        // 2 x 8 KB: 128 j x 16 k, slot-swizzled
    __shared__ float wc[2][2048];        // 2 x 8 KB: 16 k x 128 n, linear
    __shared__ float s_aggS[HH], s_aggA[HH], s_sum[HH], s_ssq[HH];

    const int t     = threadIdx.x;
    const int bi    = blockIdx.x >> 1;       // b*V + i
    const int jbase = (blockIdx.x & 1) << 7; // 0 or 128
    const int b     = bi >> 8;
    if (t < HH) { s_aggS[t]=0.f; s_aggA[t]=0.f; s_sum[t]=0.f; s_ssq[t]=0.f; }

    const int tn  = t & 15;              // n = tn*4 + qq + q*64
    const int tjg = t >> 4;              // j = tjg + jj*16   (tjg 0..15)

    float acc[8][8];
    #pragma unroll
    for (int jj = 0; jj < 8; ++jj)
        #pragma unroll
        for (int q = 0; q < 8; ++q) acc[jj][q] = 0.f;

    const f4* e4   = (const f4*)e;
    const f4* wct4 = (const f4*)WCt;

    // es staging: 128j x 16k = 512 f4; thread t handles idx t and t+256.
    // idx -> j = idx>>2, LDS slot = idx&3; global slot = (idx&3)^(j&3).
    const int j0 = t >> 2;                       // 0..63 (idx t); idx t+256 -> j0+64
    const int sp = (t & 3) ^ (j0 & 3);           // same for both (64 % 4 == 0)
    const f4* p_es0 = e4 + ((size_t)(bi*VV + jbase) + j0)*32 + sp;
    const f4* p_es1 = p_es0 + (size_t)64*32;
    const f4* p_wc  = wct4 + t;                  // idx: k=idx>>5, n4=idx&31 (linear)

    f4 r0  = p_es0[0];                           // prologue: chunk 0
    f4 r1  = p_es1[0];
    f4 rw0 = p_wc[0];
    f4 rw1 = p_wc[256];

    #pragma unroll 2
    for (int kc = 0; kc < 8; ++kc) {
        float* esb = es[kc & 1];
        float* wcb = wc[kc & 1];
        *(f4*)&esb[t*4]          = r0;           // waits vmcnt for own loads only
        *(f4*)&esb[t*4 + 1024]   = r1;
        *(f4*)&wcb[t*4]          = rw0;
        *(f4*)&wcb[t*4 + 1024]   = rw1;
        __syncthreads();                         // single barrier per chunk
        if (kc < 7) {                            // prefetch chunk kc+1 into regs;
            r0  = p_es0[(kc+1)*4];               // completes under the FMA below
            r1  = p_es1[(kc+1)*4];
            rw0 = p_wc[(kc+1)*512];
            rw1 = p_wc[(kc+1)*512 + 256];
        }
        #pragma unroll
        for (int kq = 0; kq < 4; ++kq) {         // 4-k groups within the 16-chunk
            const int sw = ((kq ^ (tjg & 3)) << 2);   // XOR-swizzled slot (floats)
            #pragma unroll
            for (int jh = 0; jh < 2; ++jh) {     // split jj to cap live aj regs
                f4 a0 = *(const f4*)&esb[(tjg + (jh*4+0)*16)*16 + sw];
                f4 a1 = *(const f4*)&esb[(tjg + (jh*4+1)*16)*16 + sw];
                f4 a2 = *(const f4*)&esb[(tjg + (jh*4+2)*16)*16 + sw];
                f4 a3 = *(const f4*)&esb[(tjg + (jh*4+3)*16)*16 + sw];
                #pragma unroll
                for (int kk = 0; kk < 4; ++kk) {
                    const float* wrow = &wcb[(kq*4 + kk)*128 + tn*4];
                    f4 w0 = *(const f4*)&wrow[0];
                    f4 w1 = *(const f4*)&wrow[64];
                    float v0 = COMP(a0,kk), v1 = COMP(a1,kk);
                    float v2 = COMP(a2,kk), v3 = COMP(a3,kk);
                    #pragma unroll
                    for (int jl = 0; jl < 4; ++jl) {
                        float a = (jl==0)?v0:(jl==1)?v1:(jl==2)?v2:v3;
                        float* ac = acc[jh*4 + jl];
                        ac[0] += a*w0.x; ac[1] += a*w0.y;
                        ac[2] += a*w0.z; ac[3] += a*w0.w;
                        ac[4] += a*w1.x; ac[5] += a*w1.y;
                        ac[6] += a*w1.z; ac[7] += a*w1.w;
                    }
                }
            }
        }
    }

    // ---- epilogue: e_new = acc + bC + Bh[i] + Ah[j]; store; stats; aggs ----
    float bcv[8], bhv[8];
    #pragma unroll
    for (int q = 0; q < 2; ++q) {
        f4 bc4 = *(const f4*)&bC[tn*4 + q*64];
        f4 bh4 = *(const f4*)&Bhw[bi*HH + tn*4 + q*64];
        bcv[q*4+0]=bc4.x; bcv[q*4+1]=bc4.y; bcv[q*4+2]=bc4.z; bcv[q*4+3]=bc4.w;
        bhv[q*4+0]=bh4.x; bhv[q*4+1]=bh4.y; bhv[q*4+2]=bh4.z; bhv[q*4+3]=bh4.w;
    }
    float sm[8], sq[8], aS[8], aA[8];
    #pragma unroll
    for (int q = 0; q < 8; ++q) { sm[q]=0.f; sq[q]=0.f; aS[q]=0.f; aA[q]=0.f; }

    const int* Sp = S + bi*VV + jbase;
    const int* Ap = A + bi*VV + jbase;
    #pragma unroll
    for (int jj = 0; jj < 8; ++jj) {
        const int j = tjg + jj*16;               // local j in [0,128)
        const int jg = jbase + j;                // global j
        const float* ahp = &Ahw[(size_t)(b*VV + jg)*HH];
        const float* vhp = &Vhw[(size_t)(b*VV + jg)*HH];
        const int Sij = Sp[j], Aij = Ap[j];
        #pragma unroll
        for (int q = 0; q < 2; ++q) {
            f4 ah = *(const f4*)&ahp[tn*4 + q*64];
            f4 vh = *(const f4*)&vhp[tn*4 + q*64];
            f4 env;
            env.x = acc[jj][q*4+0] + bcv[q*4+0] + bhv[q*4+0] + ah.x;
            env.y = acc[jj][q*4+1] + bcv[q*4+1] + bhv[q*4+1] + ah.y;
            env.z = acc[jj][q*4+2] + bcv[q*4+2] + bhv[q*4+2] + ah.z;
            env.w = acc[jj][q*4+3] + bcv[q*4+3] + bhv[q*4+3] + ah.w;
            *(f4*)&eout[((size_t)(bi*VV) + jg)*HH + tn*4 + q*64] = env;
            float vv[4] = {vh.x, vh.y, vh.z, vh.w};
            float ev[4] = {env.x, env.y, env.z, env.w};
            #pragma unroll
            for (int qq = 0; qq < 4; ++qq) {
                float v = ev[qq];
                sm[q*4+qq] += v;
                sq[q*4+qq] += v*v;
                if (!Aij) aA[q*4+qq] += vv[qq];
                if (!Sij) aS[q*4+qq] += vv[qq] * sigm(v);
            }
        }
    }
    #pragma unroll
    for (int q = 0; q < 2; ++q)
        #pragma unroll
        for (int qq = 0; qq < 4; ++qq) {
            int n = tn*4 + q*64 + qq;
            atomicAdd(&s_sum[n],  sm[q*4+qq]);
            atomicAdd(&s_ssq[n],  sq[q*4+qq]);
            atomicAdd(&s_aggS[n], aS[q*4+qq]);
            atomicAdd(&s_aggA[n], aA[q*4+qq]);
        }
    __syncthreads();
    if (t < HH) {
        atomicAdd(&aggS[bi*HH + t], s_aggS[t]);
        atomicAdd(&aggA[bi*HH + t], s_aggA[t]);
        atomicAdd(&sums[t],      s_sum[t]);   // e channel sum
        atomicAdd(&sums[HH + t], s_ssq[t]);   // e channel sumsq
    }
}

// ---------------------------------------------------------------------------
// K3a: h_new = Uh + aggS + aggA ; accumulate h channel sums
// ---------------------------------------------------------------------------
__global__ __launch_bounds__(256) void k_hnew(
    const float* __restrict__ Uh, const float* __restrict__ aggS,
    const float* __restrict__ aggA, float* __restrict__ h_new,
    float* __restrict__ sums)
{
    __shared__ float ssm[HH], ssq[HH];
    const int tid = threadIdx.x;
    if (tid < 128) { ssm[tid]=0.f; ssq[tid]=0.f; }
    __syncthreads();
    int gid = blockIdx.x*256 + tid;
    f4 u = *(const f4*)&Uh[gid*4];
    f4 s = *(const f4*)&aggS[gid*4];
    f4 a = *(const f4*)&aggA[gid*4];
    float v0=u.x+s.x+a.x, v1=u.y+s.y+a.y, v2=u.z+s.z+a.z, v3=u.w+s.w+a.w;
    *(f4*)&h_new[gid*4] = make_float4(v0,v1,v2,v3);
    int n0 = (gid*4) & 127;
    atomicAdd(&ssm[n0+0], v0); atomicAdd(&ssq[n0+0], v0*v0);
    atomicAdd(&ssm[n0+1], v1); atomicAdd(&ssq[n0+1], v1*v1);
    atomicAdd(&ssm[n0+2], v2); atomicAdd(&ssq[n0+2], v2*v2);
    atomicAdd(&ssm[n0+3], v3); atomicAdd(&ssq[n0+3], v3*v3);
    __syncthreads();
    if (tid < 128) {
        atomicAdd(&sums[256 + tid], ssm[tid]);
        atomicAdd(&sums[384 + tid], ssq[tid]);
    }
}

// ---------------------------------------------------------------------------
// K3b: finalize batchnorm params -> scale/shift per channel
// ---------------------------------------------------------------------------
__global__ void k_stats(const float* __restrict__ sums, float* __restrict__ outs,
                        const float* __restrict__ gamma_e, const float* __restrict__ beta_e,
                        const float* __restrict__ gamma_h, const float* __restrict__ beta_h)
{
    int n = threadIdx.x;   // 128
    float em  = sums[n] * (1.f/(float)NE_CNT);
    float ev  = sums[128+n] * (1.f/(float)NE_CNT) - em*em;
    float esc = rsqrtf(ev + EPSV) * gamma_e[n];
    outs[n]       = esc;
    outs[128 + n] = beta_e[n] - em*esc;
    float hm  = sums[256+n] * (1.f/1024.f);
    float hv  = sums[384+n] * (1.f/1024.f) - hm*hm;
    float hsc = rsqrtf(hv + EPSV) * gamma_h[n];
    outs[256 + n] = hsc;
    outs[384 + n] = beta_h[n] - hm*hsc;
}

// ---------------------------------------------------------------------------
// K4h: h_out = h_in + relu(bn(h_new))
// ---------------------------------------------------------------------------
__global__ __launch_bounds__(256) void k_hout(
    const float* __restrict__ h_in, const float* __restrict__ h_new,
    const float* __restrict__ outs, float* __restrict__ hout)
{
    int gid = blockIdx.x*256 + threadIdx.x;
    int n0 = (gid*4) & 127;
    f4 x  = *(const f4*)&h_new[gid*4];
    f4 hi = *(const f4*)&h_in[gid*4];
    f4 sc = *(const f4*)&outs[256 + n0];
    f4 sh = *(const f4*)&outs[384 + n0];
    f4 y;
    y.x = fmaxf(x.x*sc.x + sh.x, 0.f) + hi.x;
    y.y = fmaxf(x.y*sc.y + sh.y, 0.f) + hi.y;
    y.z = fmaxf(x.z*sc.z + sh.z, 0.f) + hi.z;
    y.w = fmaxf(x.w*sc.w + sh.w, 0.f) + hi.w;
    *(f4*)&hout[gid*4] = y;
}

// ---------------------------------------------------------------------------
// K4e: e_out = e_in + relu(bn(e_new))   (e_new lives in-place in d_out)
// ---------------------------------------------------------------------------
__global__ __launch_bounds__(256) void k_eout(
    const float* __restrict__ e_in, const float* __restrict__ outs,
    float* __restrict__ eio)
{
    size_t gid = (size_t)blockIdx.x*256 + threadIdx.x;
    int n0 = ((int)(gid & 31)) << 2;
    f4 x  = *(const f4*)&eio[gid*4];
    f4 ei = *(const f4*)&e_in[gid*4];
    f4 sc = *(const f4*)&outs[n0];
    f4 sh = *(const f4*)&outs[128 + n0];
    f4 y;
    y.x = fmaxf(x.x*sc.x + sh.x, 0.f) + ei.x;
    y.y = fmaxf(x.y*sc.y + sh.y, 0.f) + ei.y;
    y.z = fmaxf(x.z*sc.z + sh.z, 0.f) + ei.z;
    y.w = fmaxf(x.w*sc.w + sh.w, 0.f) + ei.w;
    *(f4*)&eio[gid*4] = y;
}

// ---------------------------------------------------------------------------
extern "C" void kernel_launch(void* const* d_in, const int* in_sizes, int n_in,
                              void* d_out, int out_size, void* d_ws, size_t ws_size,
                              hipStream_t stream)
{
    (void)in_sizes; (void)n_in; (void)out_size; (void)ws_size;
    const float* h   = (const float*)d_in[0];
    const float* e   = (const float*)d_in[1];
    const int*   A   = (const int*)d_in[2];
    const int*   S   = (const int*)d_in[3];
    const float* WU  = (const float*)d_in[4];   const float* bU = (const float*)d_in[5];
    const float* WV  = (const float*)d_in[6];   const float* bV = (const float*)d_in[7];
    const float* WA_ = (const float*)d_in[8];   const float* bA = (const float*)d_in[9];
    const float* WB_ = (const float*)d_in[10];  const float* bB = (const float*)d_in[11];
    const float* WC_ = (const float*)d_in[12];  const float* bC = (const float*)d_in[13];
    const float* gamma_h = (const float*)d_in[14]; const float* beta_h = (const float*)d_in[15];
    const float* gamma_e = (const float*)d_in[16]; const float* beta_e = (const float*)d_in[17];

    float* ws    = (float*)d_ws;
    float* Uh    = ws;              // 1024*128
    float* Vh    = ws + 131072;
    float* Ahw   = ws + 262144;
    float* Bhw   = ws + 393216;
    float* aggS  = ws + 524288;
    float* aggA  = ws + 655360;
    float* h_new = ws + 786432;
    float* WCt   = ws + 917504;     // 128*128
    float* sums  = ws + 933888;     // 512: e_sum, e_ssq, h_sum, h_ssq
    float* outs  = ws + 934400;     // 512: e_scale, e_shift, h_scale, h_shift

    float* hout = (float*)d_out;
    float* eout = (float*)d_out + NROWS*HH;     // e_new then e_out, in place

    hipMemsetAsync(sums, 0, 512*sizeof(float), stream);
    hipMemsetAsync(aggS, 0, 262144*sizeof(float), stream);  // aggS+aggA (contig)
    k_linear4 <<<256,   256, 0, stream>>>(h, WU,bU, WV,bV, WA_,bA, WB_,bB, Uh);
    k_transpose<<<16,   256, 0, stream>>>(WC_, WCt);
    k_edge    <<<2048,  256, 0, stream>>>(e, A, S, WCt, bC, Ahw, Bhw, Vh,
                                          eout, aggS, aggA, sums);
    k_hnew    <<<128,   256, 0, stream>>>(Uh, aggS, aggA, h_new, sums);
    k_stats   <<<1,     128, 0, stream>>>(sums, outs, gamma_e, beta_e, gamma_h, beta_h);
    k_hout    <<<128,   256, 0, stream>>>(h, h_new, outs, hout);
    k_eout    <<<32768, 256, 0, stream>>>(e, outs, eout);
}

// Round 4
// 820.274 us; speedup vs baseline: 2.1914x; 1.5711x over previous
//
#include <hip/hip_runtime.h>

#define BB 4
#define VV 256
#define HH 128
#define NROWS (BB*VV)            // 1024
#define NE_CNT (BB*VV*VV)        // 262144
#define EPSV 1e-5f

typedef float4 f4;

__device__ __forceinline__ float sigm(float x) {
    return 1.f / (1.f + __expf(-x));
}

#define COMP(v,kk) ((kk)==0 ? (v).x : (kk)==1 ? (v).y : (kk)==2 ? (v).z : (v).w)

// ---------------------------------------------------------------------------
// K1: Uh/Vh/Ah/Bh = h @ W{U,V,A,B}^T + b   (1024 x 128, K=128)
// ---------------------------------------------------------------------------
__global__ __launch_bounds__(256) void k_linear4(
    const float* __restrict__ h,
    const float* __restrict__ W0, const float* __restrict__ b0,
    const float* __restrict__ W1, const float* __restrict__ b1,
    const float* __restrict__ W2, const float* __restrict__ b2,
    const float* __restrict__ W3, const float* __restrict__ b3,
    float* __restrict__ out)
{
    __shared__ float hs[4*HH];
    const int tid = threadIdx.x;
    const int r0  = blockIdx.x * 4;
    if (tid < 128) {
        int r = tid >> 5, kq = (tid & 31) << 2;
        *(f4*)&hs[r*HH + kq] = *(const f4*)&h[(r0 + r)*HH + kq];
    }
    __syncthreads();
    const int n  = tid & 127;
    const int s0 = tid >> 7;                       // 0 or 1
    const float* Ws[4] = {W0, W1, W2, W3};
    const float* bs[4] = {b0, b1, b2, b3};
    for (int ss = 0; ss < 2; ++ss) {
        const int sel = s0 + ss*2;
        const float* wrow = Ws[sel] + n*HH;
        float a0=0.f, a1=0.f, a2=0.f, a3=0.f;
        for (int kq = 0; kq < 32; ++kq) {
            f4 w = *(const f4*)&wrow[kq<<2];
            float wq[4] = {w.x, w.y, w.z, w.w};
            #pragma unroll
            for (int q = 0; q < 4; ++q) {
                int k = (kq<<2) + q;
                float wv = wq[q];
                a0 += hs[0*HH + k] * wv;
                a1 += hs[1*HH + k] * wv;
                a2 += hs[2*HH + k] * wv;
                a3 += hs[3*HH + k] * wv;
            }
        }
        float bias = bs[sel][n];
        float* o = out + sel*(NROWS*HH);
        o[(r0+0)*HH + n] = a0 + bias;
        o[(r0+1)*HH + n] = a1 + bias;
        o[(r0+2)*HH + n] = a2 + bias;
        o[(r0+3)*HH + n] = a3 + bias;
    }
}

// ---------------------------------------------------------------------------
// K1b: WCt[k][n] = WC[n][k]  (128x128, LDS-tiled transpose)
// ---------------------------------------------------------------------------
__global__ __launch_bounds__(256) void k_transpose(
    const float* __restrict__ in, float* __restrict__ out)
{
    __shared__ float t[32][33];
    int ti = blockIdx.x >> 2, tj = blockIdx.x & 3;
    int tx = threadIdx.x & 31, ty = threadIdx.x >> 5;   // ty 0..7
    for (int yy = ty; yy < 32; yy += 8)
        t[yy][tx] = in[(ti*32 + yy)*HH + tj*32 + tx];
    __syncthreads();
    for (int yy = ty; yy < 32; yy += 8)
        out[(tj*32 + yy)*HH + ti*32 + tx] = t[tx][yy];
}

// ---------------------------------------------------------------------------
// K2 v5: per block: half-row Ce GEMM (128j x 128n, K=128) + e_new epilogue.
//
// v3/v4 post-mortem: on this toolchain the 2nd __launch_bounds__ arg behaves
// as cap = 512/(2*arg): (256,2)->128 VGPR, (512,4)->64, (256,3)->84. v4's
// (256,3) therefore capped at ~85 while the kernel needs ~120 -> scratch
// spill (FETCH 1.4GB, WRITE 2.3GB, VALUBusy 8%). Fix: (256,2) -> cap 128,
// and the pipeline is budgeted to fit: acc 64 + prefetch 16 + addr ~30.
//  - 256 threads, block tile 128j x 128n (grid 2048: bi x jhalf).
//  - per-thread 8j x 8n, direct constant acc indexing (no pointer aliasing).
//  - K-chunk 16, es/wc double-buffered (16+16 KB LDS), ONE barrier/chunk;
//    next chunk's global loads issue right after the barrier and complete
//    under ~2000cy of FMA (T14 async-split).
//  - es slot-XOR swizzle (s ^ j&3 both sides): conflict-free ds_read_b128.
//  - LDS 34 KB + VGPR 128 -> 4 blocks/CU = 16 waves/CU (vs v2's 7).
// ---------------------------------------------------------------------------
__global__ __launch_bounds__(256, 2) void k_edge(
    const float* __restrict__ e, const int* __restrict__ A, const int* __restrict__ S,
    const float* __restrict__ WCt, const float* __restrict__ bC,
    const float* __restrict__ Ahw, const float* __restrict__ Bhw,
    const float* __restrict__ Vhw,
    float* __restrict__ eout, float* __restrict__ aggS, float* __restrict__ aggA,
    float* __restrict__ sums)
{
    __shared__ float es[2][2048];        // 2 x 8 KB: 128 j x 16 k, slot-swizzled
    __shared__ float wc[2][2048];        // 2 x 8 KB: 16 k x 128 n, linear
    __shared__ float s_aggS[HH], s_aggA[HH], s_sum[HH], s_ssq[HH];

    const int t     = threadIdx.x;
    const int bi    = blockIdx.x >> 1;       // b*V + i
    const int jbase = (blockIdx.x & 1) << 7; // 0 or 128
    const int b     = bi >> 8;
    if (t < HH) { s_aggS[t]=0.f; s_aggA[t]=0.f; s_sum[t]=0.f; s_ssq[t]=0.f; }

    const int tn  = t & 15;              // n = tn*4 + qq + q*64
    const int tjg = t >> 4;              // j = tjg + jj*16   (tjg 0..15)

    float acc[8][8];
    #pragma unroll
    for (int jj = 0; jj < 8; ++jj)
        #pragma unroll
        for (int q = 0; q < 8; ++q) acc[jj][q] = 0.f;

    const f4* e4   = (const f4*)e;
    const f4* wct4 = (const f4*)WCt;

    // es staging: 128j x 16k = 512 f4; thread t handles idx t and t+256.
    // idx -> j = idx>>2, LDS slot = idx&3; global slot = (idx&3)^(j&3).
    const int j0 = t >> 2;                       // 0..63 (idx t); idx t+256 -> j0+64
    const int sp = (t & 3) ^ (j0 & 3);           // same for both (64 % 4 == 0)
    const f4* p_es0 = e4 + ((size_t)(bi*VV + jbase) + j0)*32 + sp;
    const f4* p_es1 = p_es0 + (size_t)64*32;
    const f4* p_wc  = wct4 + t;                  // idx: k=idx>>5, n4=idx&31 (linear)

    f4 r0  = p_es0[0];                           // prologue: chunk 0
    f4 r1  = p_es1[0];
    f4 rw0 = p_wc[0];
    f4 rw1 = p_wc[256];

    #pragma unroll 2
    for (int kc = 0; kc < 8; ++kc) {
        float* esb = es[kc & 1];
        float* wcb = wc[kc & 1];
        *(f4*)&esb[t*4]          = r0;           // waits vmcnt for own loads only
        *(f4*)&esb[t*4 + 1024]   = r1;
        *(f4*)&wcb[t*4]          = rw0;
        *(f4*)&wcb[t*4 + 1024]   = rw1;
        __syncthreads();                         // single barrier per chunk
        if (kc < 7) {                            // prefetch chunk kc+1 into regs;
            r0  = p_es0[(kc+1)*4];               // completes under the FMA below
            r1  = p_es1[(kc+1)*4];
            rw0 = p_wc[(kc+1)*512];
            rw1 = p_wc[(kc+1)*512 + 256];
        }
        #pragma unroll
        for (int kq = 0; kq < 4; ++kq) {         // 4-k groups within the 16-chunk
            const int sw = ((kq ^ (tjg & 3)) << 2);   // XOR-swizzled slot (floats)
            #pragma unroll
            for (int jh = 0; jh < 2; ++jh) {     // split jj to cap live aj regs
                f4 a0 = *(const f4*)&esb[(tjg + (jh*4+0)*16)*16 + sw];
                f4 a1 = *(const f4*)&esb[(tjg + (jh*4+1)*16)*16 + sw];
                f4 a2 = *(const f4*)&esb[(tjg + (jh*4+2)*16)*16 + sw];
                f4 a3 = *(const f4*)&esb[(tjg + (jh*4+3)*16)*16 + sw];
                #pragma unroll
                for (int kk = 0; kk < 4; ++kk) {
                    const float* wrow = &wcb[(kq*4 + kk)*128 + tn*4];
                    f4 w0 = *(const f4*)&wrow[0];
                    f4 w1 = *(const f4*)&wrow[64];
                    float v0 = COMP(a0,kk), v1 = COMP(a1,kk);
                    float v2 = COMP(a2,kk), v3 = COMP(a3,kk);
                    #pragma unroll
                    for (int jl = 0; jl < 4; ++jl) {
                        float a = (jl==0)?v0:(jl==1)?v1:(jl==2)?v2:v3;
                        acc[jh*4+jl][0] += a*w0.x;
                        acc[jh*4+jl][1] += a*w0.y;
                        acc[jh*4+jl][2] += a*w0.z;
                        acc[jh*4+jl][3] += a*w0.w;
                        acc[jh*4+jl][4] += a*w1.x;
                        acc[jh*4+jl][5] += a*w1.y;
                        acc[jh*4+jl][6] += a*w1.z;
                        acc[jh*4+jl][7] += a*w1.w;
                    }
                }
            }
        }
    }

    // ---- epilogue: e_new = acc + bC + Bh[i] + Ah[j]; store; stats; aggs ----
    float bcv[8], bhv[8];
    #pragma unroll
    for (int q = 0; q < 2; ++q) {
        f4 bc4 = *(const f4*)&bC[tn*4 + q*64];
        f4 bh4 = *(const f4*)&Bhw[bi*HH + tn*4 + q*64];
        bcv[q*4+0]=bc4.x; bcv[q*4+1]=bc4.y; bcv[q*4+2]=bc4.z; bcv[q*4+3]=bc4.w;
        bhv[q*4+0]=bh4.x; bhv[q*4+1]=bh4.y; bhv[q*4+2]=bh4.z; bhv[q*4+3]=bh4.w;
    }
    float sm[8], sq[8], aS[8], aA[8];
    #pragma unroll
    for (int q = 0; q < 8; ++q) { sm[q]=0.f; sq[q]=0.f; aS[q]=0.f; aA[q]=0.f; }

    const int* Sp = S + bi*VV + jbase;
    const int* Ap = A + bi*VV + jbase;
    #pragma unroll
    for (int jj = 0; jj < 8; ++jj) {
        const int j = tjg + jj*16;               // local j in [0,128)
        const int jg = jbase + j;                // global j
        const float* ahp = &Ahw[(size_t)(b*VV + jg)*HH];
        const float* vhp = &Vhw[(size_t)(b*VV + jg)*HH];
        const int Sij = Sp[j], Aij = Ap[j];
        #pragma unroll
        for (int q = 0; q < 2; ++q) {
            f4 ah = *(const f4*)&ahp[tn*4 + q*64];
            f4 vh = *(const f4*)&vhp[tn*4 + q*64];
            f4 env;
            env.x = acc[jj][q*4+0] + bcv[q*4+0] + bhv[q*4+0] + ah.x;
            env.y = acc[jj][q*4+1] + bcv[q*4+1] + bhv[q*4+1] + ah.y;
            env.z = acc[jj][q*4+2] + bcv[q*4+2] + bhv[q*4+2] + ah.z;
            env.w = acc[jj][q*4+3] + bcv[q*4+3] + bhv[q*4+3] + ah.w;
            *(f4*)&eout[((size_t)(bi*VV) + jg)*HH + tn*4 + q*64] = env;
            float vv[4] = {vh.x, vh.y, vh.z, vh.w};
            float ev[4] = {env.x, env.y, env.z, env.w};
            #pragma unroll
            for (int qq = 0; qq < 4; ++qq) {
                float v = ev[qq];
                sm[q*4+qq] += v;
                sq[q*4+qq] += v*v;
                if (!Aij) aA[q*4+qq] += vv[qq];
                if (!Sij) aS[q*4+qq] += vv[qq] * sigm(v);
            }
        }
    }
    #pragma unroll
    for (int q = 0; q < 2; ++q)
        #pragma unroll
        for (int qq = 0; qq < 4; ++qq) {
            int n = tn*4 + q*64 + qq;
            atomicAdd(&s_sum[n],  sm[q*4+qq]);
            atomicAdd(&s_ssq[n],  sq[q*4+qq]);
            atomicAdd(&s_aggS[n], aS[q*4+qq]);
            atomicAdd(&s_aggA[n], aA[q*4+qq]);
        }
    __syncthreads();
    if (t < HH) {
        atomicAdd(&aggS[bi*HH + t], s_aggS[t]);
        atomicAdd(&aggA[bi*HH + t], s_aggA[t]);
        atomicAdd(&sums[t],      s_sum[t]);   // e channel sum
        atomicAdd(&sums[HH + t], s_ssq[t]);   // e channel sumsq
    }
}

// ---------------------------------------------------------------------------
// K3a: h_new = Uh + aggS + aggA ; accumulate h channel sums
// ---------------------------------------------------------------------------
__global__ __launch_bounds__(256) void k_hnew(
    const float* __restrict__ Uh, const float* __restrict__ aggS,
    const float* __restrict__ aggA, float* __restrict__ h_new,
    float* __restrict__ sums)
{
    __shared__ float ssm[HH], ssq[HH];
    const int tid = threadIdx.x;
    if (tid < 128) { ssm[tid]=0.f; ssq[tid]=0.f; }
    __syncthreads();
    int gid = blockIdx.x*256 + tid;
    f4 u = *(const f4*)&Uh[gid*4];
    f4 s = *(const f4*)&aggS[gid*4];
    f4 a = *(const f4*)&aggA[gid*4];
    float v0=u.x+s.x+a.x, v1=u.y+s.y+a.y, v2=u.z+s.z+a.z, v3=u.w+s.w+a.w;
    *(f4*)&h_new[gid*4] = make_float4(v0,v1,v2,v3);
    int n0 = (gid*4) & 127;
    atomicAdd(&ssm[n0+0], v0); atomicAdd(&ssq[n0+0], v0*v0);
    atomicAdd(&ssm[n0+1], v1); atomicAdd(&ssq[n0+1], v1*v1);
    atomicAdd(&ssm[n0+2], v2); atomicAdd(&ssq[n0+2], v2*v2);
    atomicAdd(&ssm[n0+3], v3); atomicAdd(&ssq[n0+3], v3*v3);
    __syncthreads();
    if (tid < 128) {
        atomicAdd(&sums[256 + tid], ssm[tid]);
        atomicAdd(&sums[384 + tid], ssq[tid]);
    }
}

// ---------------------------------------------------------------------------
// K3b: finalize batchnorm params -> scale/shift per channel
// ---------------------------------------------------------------------------
__global__ void k_stats(const float* __restrict__ sums, float* __restrict__ outs,
                        const float* __restrict__ gamma_e, const float* __restrict__ beta_e,
                        const float* __restrict__ gamma_h, const float* __restrict__ beta_h)
{
    int n = threadIdx.x;   // 128
    float em  = sums[n] * (1.f/(float)NE_CNT);
    float ev  = sums[128+n] * (1.f/(float)NE_CNT) - em*em;
    float esc = rsqrtf(ev + EPSV) * gamma_e[n];
    outs[n]       = esc;
    outs[128 + n] = beta_e[n] - em*esc;
    float hm  = sums[256+n] * (1.f/1024.f);
    float hv  = sums[384+n] * (1.f/1024.f) - hm*hm;
    float hsc = rsqrtf(hv + EPSV) * gamma_h[n];
    outs[256 + n] = hsc;
    outs[384 + n] = beta_h[n] - hm*hsc;
}

// ---------------------------------------------------------------------------
// K4h: h_out = h_in + relu(bn(h_new))
// ---------------------------------------------------------------------------
__global__ __launch_bounds__(256) void k_hout(
    const float* __restrict__ h_in, const float* __restrict__ h_new,
    const float* __restrict__ outs, float* __restrict__ hout)
{
    int gid = blockIdx.x*256 + threadIdx.x;
    int n0 = (gid*4) & 127;
    f4 x  = *(const f4*)&h_new[gid*4];
    f4 hi = *(const f4*)&h_in[gid*4];
    f4 sc = *(const f4*)&outs[256 + n0];
    f4 sh = *(const f4*)&outs[384 + n0];
    f4 y;
    y.x = fmaxf(x.x*sc.x + sh.x, 0.f) + hi.x;
    y.y = fmaxf(x.y*sc.y + sh.y, 0.f) + hi.y;
    y.z = fmaxf(x.z*sc.z + sh.z, 0.f) + hi.z;
    y.w = fmaxf(x.w*sc.w + sh.w, 0.f) + hi.w;
    *(f4*)&hout[gid*4] = y;
}

// ---------------------------------------------------------------------------
// K4e: e_out = e_in + relu(bn(e_new))   (e_new lives in-place in d_out)
// ---------------------------------------------------------------------------
__global__ __launch_bounds__(256) void k_eout(
    const float* __restrict__ e_in, const float* __restrict__ outs,
    float* __restrict__ eio)
{
    size_t gid = (size_t)blockIdx.x*256 + threadIdx.x;
    int n0 = ((int)(gid & 31)) << 2;
    f4 x  = *(const f4*)&eio[gid*4];
    f4 ei = *(const f4*)&e_in[gid*4];
    f4 sc = *(const f4*)&outs[n0];
    f4 sh = *(const f4*)&outs[128 + n0];
    f4 y;
    y.x = fmaxf(x.x*sc.x + sh.x, 0.f) + ei.x;
    y.y = fmaxf(x.y*sc.y + sh.y, 0.f) + ei.y;
    y.z = fmaxf(x.z*sc.z + sh.z, 0.f) + ei.z;
    y.w = fmaxf(x.w*sc.w + sh.w, 0.f) + ei.w;
    *(f4*)&eio[gid*4] = y;
}

// ---------------------------------------------------------------------------
extern "C" void kernel_launch(void* const* d_in, const int* in_sizes, int n_in,
                              void* d_out, int out_size, void* d_ws, size_t ws_size,
                              hipStream_t stream)
{
    (void)in_sizes; (void)n_in; (void)out_size; (void)ws_size;
    const float* h   = (const float*)d_in[0];
    const float* e   = (const float*)d_in[1];
    const int*   A   = (const int*)d_in[2];
    const int*   S   = (const int*)d_in[3];
    const float* WU  = (const float*)d_in[4];   const float* bU = (const float*)d_in[5];
    const float* WV  = (const float*)d_in[6];   const float* bV = (const float*)d_in[7];
    const float* WA_ = (const float*)d_in[8];   const float* bA = (const float*)d_in[9];
    const float* WB_ = (const float*)d_in[10];  const float* bB = (const float*)d_in[11];
    const float* WC_ = (const float*)d_in[12];  const float* bC = (const float*)d_in[13];
    const float* gamma_h = (const float*)d_in[14]; const float* beta_h = (const float*)d_in[15];
    const float* gamma_e = (const float*)d_in[16]; const float* beta_e = (const float*)d_in[17];

    float* ws    = (float*)d_ws;
    float* Uh    = ws;              // 1024*128
    float* Vh    = ws + 131072;
    float* Ahw   = ws + 262144;
    float* Bhw   = ws + 393216;
    float* aggS  = ws + 524288;
    float* aggA  = ws + 655360;
    float* h_new = ws + 786432;
    float* WCt   = ws + 917504;     // 128*128
    float* sums  = ws + 933888;     // 512: e_sum, e_ssq, h_sum, h_ssq
    float* outs  = ws + 934400;     // 512: e_scale, e_shift, h_scale, h_shift

    float* hout = (float*)d_out;
    float* eout = (float*)d_out + NROWS*HH;     // e_new then e_out, in place

    hipMemsetAsync(sums, 0, 512*sizeof(float), stream);
    hipMemsetAsync(aggS, 0, 262144*sizeof(float), stream);  // aggS+aggA (contig)
    k_linear4 <<<256,   256, 0, stream>>>(h, WU,bU, WV,bV, WA_,bA, WB_,bB, Uh);
    k_transpose<<<16,   256, 0, stream>>>(WC_, WCt);
    k_edge    <<<2048,  256, 0, stream>>>(e, A, S, WCt, bC, Ahw, Bhw, Vh,
                                          eout, aggS, aggA, sums);
    k_hnew    <<<128,   256, 0, stream>>>(Uh, aggS, aggA, h_new, sums);
    k_stats   <<<1,     128, 0, stream>>>(sums, outs, gamma_e, beta_e, gamma_h, beta_h);
    k_hout    <<<128,   256, 0, stream>>>(h, h_new, outs, hout);
    k_eout    <<<32768, 256, 0, stream>>>(e, outs, eout);
}

// Round 5
// 510.796 us; speedup vs baseline: 3.5191x; 1.6059x over previous
//
#include <hip/hip_runtime.h>

#define BB 4
#define VV 256
#define HH 128
#define NROWS (BB*VV)            // 1024
#define NE_CNT (BB*VV*VV)        // 262144
#define EPSV 1e-5f

typedef float4 f4;

__device__ __forceinline__ float sigm(float x) {
    return 1.f / (1.f + __expf(-x));
}

#define COMP(v,kk) ((kk)==0 ? (v).x : (kk)==1 ? (v).y : (kk)==2 ? (v).z : (v).w)

// async HBM->LDS, 16B per lane; LDS dest = wave-uniform base + lane*16
#define GLOAD_LDS16(g, l) __builtin_amdgcn_global_load_lds( \
    (const __attribute__((address_space(1))) unsigned int*)(g), \
    (__attribute__((address_space(3))) unsigned int*)(l), 16, 0, 0)

// ---------------------------------------------------------------------------
// K1: Uh/Vh/Ah/Bh = h @ W{U,V,A,B}^T + b   (1024 x 128, K=128)
// ---------------------------------------------------------------------------
__global__ __launch_bounds__(256) void k_linear4(
    const float* __restrict__ h,
    const float* __restrict__ W0, const float* __restrict__ b0,
    const float* __restrict__ W1, const float* __restrict__ b1,
    const float* __restrict__ W2, const float* __restrict__ b2,
    const float* __restrict__ W3, const float* __restrict__ b3,
    float* __restrict__ out)
{
    __shared__ float hs[4*HH];
    const int tid = threadIdx.x;
    const int r0  = blockIdx.x * 4;
    if (tid < 128) {
        int r = tid >> 5, kq = (tid & 31) << 2;
        *(f4*)&hs[r*HH + kq] = *(const f4*)&h[(r0 + r)*HH + kq];
    }
    __syncthreads();
    const int n  = tid & 127;
    const int s0 = tid >> 7;                       // 0 or 1
    const float* Ws[4] = {W0, W1, W2, W3};
    const float* bs[4] = {b0, b1, b2, b3};
    for (int ss = 0; ss < 2; ++ss) {
        const int sel = s0 + ss*2;
        const float* wrow = Ws[sel] + n*HH;
        float a0=0.f, a1=0.f, a2=0.f, a3=0.f;
        for (int kq = 0; kq < 32; ++kq) {
            f4 w = *(const f4*)&wrow[kq<<2];
            float wq[4] = {w.x, w.y, w.z, w.w};
            #pragma unroll
            for (int q = 0; q < 4; ++q) {
                int k = (kq<<2) + q;
                float wv = wq[q];
                a0 += hs[0*HH + k] * wv;
                a1 += hs[1*HH + k] * wv;
                a2 += hs[2*HH + k] * wv;
                a3 += hs[3*HH + k] * wv;
            }
        }
        float bias = bs[sel][n];
        float* o = out + sel*(NROWS*HH);
        o[(r0+0)*HH + n] = a0 + bias;
        o[(r0+1)*HH + n] = a1 + bias;
        o[(r0+2)*HH + n] = a2 + bias;
        o[(r0+3)*HH + n] = a3 + bias;
    }
}

// ---------------------------------------------------------------------------
// K1b: WCt[k][n] = WC[n][k]  (128x128, LDS-tiled transpose)
// ---------------------------------------------------------------------------
__global__ __launch_bounds__(256) void k_transpose(
    const float* __restrict__ in, float* __restrict__ out)
{
    __shared__ float t[32][33];
    int ti = blockIdx.x >> 2, tj = blockIdx.x & 3;
    int tx = threadIdx.x & 31, ty = threadIdx.x >> 5;   // ty 0..7
    for (int yy = ty; yy < 32; yy += 8)
        t[yy][tx] = in[(ti*32 + yy)*HH + tj*32 + tx];
    __syncthreads();
    for (int yy = ty; yy < 32; yy += 8)
        out[(tj*32 + yy)*HH + ti*32 + tx] = t[tx][yy];
}

// ---------------------------------------------------------------------------
// K2 v6: per block: half-row Ce GEMM (128j x 128n, K=128) + e_new epilogue.
//
// v5 post-mortem: register prefetch (16 f4 live across the barrier, x2 via
// unroll) pushed ARCH-VGPR demand past the 128 budget of (256,2) -> memory
// spill (FETCH 744MB/WRITE 1.17GB, VALUBusy 15%). The fix is structural:
// __builtin_amdgcn_global_load_lds stages HBM->LDS with ZERO staging regs.
// T3-minimal 2-phase (m230 template):
//   STAGE(buf^1, kc+1) async -> ds_read+FMA on buf -> one barrier/chunk.
// The barrier's vmcnt(0) drain lands after ~2000cy of FMA, so the async
// loads are complete; staging latency fully hidden.
//  - LDS layout stays LINEAR in lane order (gload_lds requirement); the
//    es XOR swizzle is applied on the per-lane GLOBAL address (m173) and
//    on the ds_read side -- both-sides-or-neither (rule #21) holds.
//  - main-loop live regs: acc 64 + aj 16 + w 8 + addr ~15 < 128 budget.
//  - LDS 34 KB, (256,2): known-good config (v2 ran it spill-free).
// ---------------------------------------------------------------------------
__global__ __launch_bounds__(256, 2) void k_edge(
    const float* __restrict__ e, const int* __restrict__ A, const int* __restrict__ S,
    const float* __restrict__ WCt, const float* __restrict__ bC,
    const float* __restrict__ Ahw, const float* __restrict__ Bhw,
    const float* __restrict__ Vhw,
    float* __restrict__ eout, float* __restrict__ aggS, float* __restrict__ aggA,
    float* __restrict__ sums)
{
    __shared__ float es[2][2048];        // 2 x 8 KB: 128 j x 16 k, slot-swizzled
    __shared__ float wc[2][2048];        // 2 x 8 KB: 16 k x 128 n, linear
    __shared__ float s_aggS[HH], s_aggA[HH], s_sum[HH], s_ssq[HH];

    const int t     = threadIdx.x;
    const int bi    = blockIdx.x >> 1;       // b*V + i
    const int jbase = (blockIdx.x & 1) << 7; // 0 or 128
    const int b     = bi >> 8;
    if (t < HH) { s_aggS[t]=0.f; s_aggA[t]=0.f; s_sum[t]=0.f; s_ssq[t]=0.f; }

    const int tn  = t & 15;              // n = tn*4 + qq + q*64
    const int tjg = t >> 4;              // j = tjg + jj*16   (tjg 0..15)

    float acc[8][8];
    #pragma unroll
    for (int jj = 0; jj < 8; ++jj)
        #pragma unroll
        for (int q = 0; q < 8; ++q) acc[jj][q] = 0.f;

    const f4* e4   = (const f4*)e;
    const f4* wct4 = (const f4*)WCt;

    // es staging: 128j x 16k = 512 f4/chunk; element idx = {t, t+256}.
    // idx -> j = idx>>2, LDS slot = idx&3; global slot = (idx&3)^(j&3)
    // (swizzle on the GLOBAL address; LDS stays linear for gload_lds).
    const int j0 = t >> 2;                       // idx=t -> j0; idx=t+256 -> j0+64
    const int sp = (t & 3) ^ (j0 & 3);           // same for both (64%4==0)
    const f4* p_es0 = e4 + ((size_t)(bi*VV + jbase) + j0)*32 + sp;
    const f4* p_es1 = p_es0 + (size_t)64*32;
    const f4* p_wc  = wct4 + t;                  // linear: k=idx>>5, n4=idx&31

    // wave-uniform LDS bases: lane i lands at base + i*16B
    const int wave = t >> 6;                     // 0..3
    const int wofs = wave * 256;                 // floats: 64 lanes * 4 floats

    #define STAGE(buf, kc_) do {                                        \
        float* esb_ = es[buf];                                          \
        float* wcb_ = wc[buf];                                          \
        GLOAD_LDS16(p_es0 + (kc_)*4,        &esb_[wofs]);               \
        GLOAD_LDS16(p_es1 + (kc_)*4,        &esb_[1024 + wofs]);        \
        GLOAD_LDS16(p_wc  + (kc_)*512,      &wcb_[wofs]);               \
        GLOAD_LDS16(p_wc  + (kc_)*512+256,  &wcb_[1024 + wofs]);        \
    } while (0)

    STAGE(0, 0);                                 // prologue: chunk 0
    __syncthreads();                             // vmcnt(0) drain + barrier

    for (int kc = 0; kc < 8; ++kc) {
        float* esb = es[kc & 1];
        float* wcb = wc[kc & 1];
        if (kc < 7) STAGE((kc & 1) ^ 1, kc + 1); // async prefetch, other buffer
        #pragma unroll
        for (int kq = 0; kq < 4; ++kq) {         // 4-k groups within the 16-chunk
            const int sw = ((kq ^ (tjg & 3)) << 2);   // XOR-swizzled slot (floats)
            #pragma unroll
            for (int jh = 0; jh < 2; ++jh) {     // split jj to cap live aj regs
                f4 a0 = *(const f4*)&esb[(tjg + (jh*4+0)*16)*16 + sw];
                f4 a1 = *(const f4*)&esb[(tjg + (jh*4+1)*16)*16 + sw];
                f4 a2 = *(const f4*)&esb[(tjg + (jh*4+2)*16)*16 + sw];
                f4 a3 = *(const f4*)&esb[(tjg + (jh*4+3)*16)*16 + sw];
                #pragma unroll
                for (int kk = 0; kk < 4; ++kk) {
                    const float* wrow = &wcb[(kq*4 + kk)*128 + tn*4];
                    f4 w0 = *(const f4*)&wrow[0];
                    f4 w1 = *(const f4*)&wrow[64];
                    float v0 = COMP(a0,kk), v1 = COMP(a1,kk);
                    float v2 = COMP(a2,kk), v3 = COMP(a3,kk);
                    #pragma unroll
                    for (int jl = 0; jl < 4; ++jl) {
                        float a = (jl==0)?v0:(jl==1)?v1:(jl==2)?v2:v3;
                        acc[jh*4+jl][0] += a*w0.x;
                        acc[jh*4+jl][1] += a*w0.y;
                        acc[jh*4+jl][2] += a*w0.z;
                        acc[jh*4+jl][3] += a*w0.w;
                        acc[jh*4+jl][4] += a*w1.x;
                        acc[jh*4+jl][5] += a*w1.y;
                        acc[jh*4+jl][6] += a*w1.z;
                        acc[jh*4+jl][7] += a*w1.w;
                    }
                }
            }
        }
        __syncthreads();                         // drains prefetch (done) + fence
    }
    #undef STAGE

    // ---- epilogue: e_new = acc + bC + Bh[i] + Ah[j]; store; stats; aggs ----
    float bcv[8], bhv[8];
    #pragma unroll
    for (int q = 0; q < 2; ++q) {
        f4 bc4 = *(const f4*)&bC[tn*4 + q*64];
        f4 bh4 = *(const f4*)&Bhw[bi*HH + tn*4 + q*64];
        bcv[q*4+0]=bc4.x; bcv[q*4+1]=bc4.y; bcv[q*4+2]=bc4.z; bcv[q*4+3]=bc4.w;
        bhv[q*4+0]=bh4.x; bhv[q*4+1]=bh4.y; bhv[q*4+2]=bh4.z; bhv[q*4+3]=bh4.w;
    }
    float sm[8], sq[8], aS[8], aA[8];
    #pragma unroll
    for (int q = 0; q < 8; ++q) { sm[q]=0.f; sq[q]=0.f; aS[q]=0.f; aA[q]=0.f; }

    const int* Sp = S + bi*VV + jbase;
    const int* Ap = A + bi*VV + jbase;
    #pragma unroll
    for (int jj = 0; jj < 8; ++jj) {
        const int j = tjg + jj*16;               // local j in [0,128)
        const int jg = jbase + j;                // global j
        const float* ahp = &Ahw[(size_t)(b*VV + jg)*HH];
        const float* vhp = &Vhw[(size_t)(b*VV + jg)*HH];
        const int Sij = Sp[j], Aij = Ap[j];
        #pragma unroll
        for (int q = 0; q < 2; ++q) {
            f4 ah = *(const f4*)&ahp[tn*4 + q*64];
            f4 vh = *(const f4*)&vhp[tn*4 + q*64];
            f4 env;
            env.x = acc[jj][q*4+0] + bcv[q*4+0] + bhv[q*4+0] + ah.x;
            env.y = acc[jj][q*4+1] + bcv[q*4+1] + bhv[q*4+1] + ah.y;
            env.z = acc[jj][q*4+2] + bcv[q*4+2] + bhv[q*4+2] + ah.z;
            env.w = acc[jj][q*4+3] + bcv[q*4+3] + bhv[q*4+3] + ah.w;
            *(f4*)&eout[((size_t)(bi*VV) + jg)*HH + tn*4 + q*64] = env;
            float vv[4] = {vh.x, vh.y, vh.z, vh.w};
            float ev[4] = {env.x, env.y, env.z, env.w};
            #pragma unroll
            for (int qq = 0; qq < 4; ++qq) {
                float v = ev[qq];
                sm[q*4+qq] += v;
                sq[q*4+qq] += v*v;
                if (!Aij) aA[q*4+qq] += vv[qq];
                if (!Sij) aS[q*4+qq] += vv[qq] * sigm(v);
            }
        }
    }
    #pragma unroll
    for (int q = 0; q < 2; ++q)
        #pragma unroll
        for (int qq = 0; qq < 4; ++qq) {
            int n = tn*4 + q*64 + qq;
            atomicAdd(&s_sum[n],  sm[q*4+qq]);
            atomicAdd(&s_ssq[n],  sq[q*4+qq]);
            atomicAdd(&s_aggS[n], aS[q*4+qq]);
            atomicAdd(&s_aggA[n], aA[q*4+qq]);
        }
    __syncthreads();
    if (t < HH) {
        atomicAdd(&aggS[bi*HH + t], s_aggS[t]);
        atomicAdd(&aggA[bi*HH + t], s_aggA[t]);
        atomicAdd(&sums[t],      s_sum[t]);   // e channel sum
        atomicAdd(&sums[HH + t], s_ssq[t]);   // e channel sumsq
    }
}

// ---------------------------------------------------------------------------
// K3a: h_new = Uh + aggS + aggA ; accumulate h channel sums
// ---------------------------------------------------------------------------
__global__ __launch_bounds__(256) void k_hnew(
    const float* __restrict__ Uh, const float* __restrict__ aggS,
    const float* __restrict__ aggA, float* __restrict__ h_new,
    float* __restrict__ sums)
{
    __shared__ float ssm[HH], ssq[HH];
    const int tid = threadIdx.x;
    if (tid < 128) { ssm[tid]=0.f; ssq[tid]=0.f; }
    __syncthreads();
    int gid = blockIdx.x*256 + tid;
    f4 u = *(const f4*)&Uh[gid*4];
    f4 s = *(const f4*)&aggS[gid*4];
    f4 a = *(const f4*)&aggA[gid*4];
    float v0=u.x+s.x+a.x, v1=u.y+s.y+a.y, v2=u.z+s.z+a.z, v3=u.w+s.w+a.w;
    *(f4*)&h_new[gid*4] = make_float4(v0,v1,v2,v3);
    int n0 = (gid*4) & 127;
    atomicAdd(&ssm[n0+0], v0); atomicAdd(&ssq[n0+0], v0*v0);
    atomicAdd(&ssm[n0+1], v1); atomicAdd(&ssq[n0+1], v1*v1);
    atomicAdd(&ssm[n0+2], v2); atomicAdd(&ssq[n0+2], v2*v2);
    atomicAdd(&ssm[n0+3], v3); atomicAdd(&ssq[n0+3], v3*v3);
    __syncthreads();
    if (tid < 128) {
        atomicAdd(&sums[256 + tid], ssm[tid]);
        atomicAdd(&sums[384 + tid], ssq[tid]);
    }
}

// ---------------------------------------------------------------------------
// K3b: finalize batchnorm params -> scale/shift per channel
// ---------------------------------------------------------------------------
__global__ void k_stats(const float* __restrict__ sums, float* __restrict__ outs,
                        const float* __restrict__ gamma_e, const float* __restrict__ beta_e,
                        const float* __restrict__ gamma_h, const float* __restrict__ beta_h)
{
    int n = threadIdx.x;   // 128
    float em  = sums[n] * (1.f/(float)NE_CNT);
    float ev  = sums[128+n] * (1.f/(float)NE_CNT) - em*em;
    float esc = rsqrtf(ev + EPSV) * gamma_e[n];
    outs[n]       = esc;
    outs[128 + n] = beta_e[n] - em*esc;
    float hm  = sums[256+n] * (1.f/1024.f);
    float hv  = sums[384+n] * (1.f/1024.f) - hm*hm;
    float hsc = rsqrtf(hv + EPSV) * gamma_h[n];
    outs[256 + n] = hsc;
    outs[384 + n] = beta_h[n] - hm*hsc;
}

// ---------------------------------------------------------------------------
// K4h: h_out = h_in + relu(bn(h_new))
// ---------------------------------------------------------------------------
__global__ __launch_bounds__(256) void k_hout(
    const float* __restrict__ h_in, const float* __restrict__ h_new,
    const float* __restrict__ outs, float* __restrict__ hout)
{
    int gid = blockIdx.x*256 + threadIdx.x;
    int n0 = (gid*4) & 127;
    f4 x  = *(const f4*)&h_new[gid*4];
    f4 hi = *(const f4*)&h_in[gid*4];
    f4 sc = *(const f4*)&outs[256 + n0];
    f4 sh = *(const f4*)&outs[384 + n0];
    f4 y;
    y.x = fmaxf(x.x*sc.x + sh.x, 0.f) + hi.x;
    y.y = fmaxf(x.y*sc.y + sh.y, 0.f) + hi.y;
    y.z = fmaxf(x.z*sc.z + sh.z, 0.f) + hi.z;
    y.w = fmaxf(x.w*sc.w + sh.w, 0.f) + hi.w;
    *(f4*)&hout[gid*4] = y;
}

// ---------------------------------------------------------------------------
// K4e: e_out = e_in + relu(bn(e_new))   (e_new lives in-place in d_out)
// ---------------------------------------------------------------------------
__global__ __launch_bounds__(256) void k_eout(
    const float* __restrict__ e_in, const float* __restrict__ outs,
    float* __restrict__ eio)
{
    size_t gid = (size_t)blockIdx.x*256 + threadIdx.x;
    int n0 = ((int)(gid & 31)) << 2;
    f4 x  = *(const f4*)&eio[gid*4];
    f4 ei = *(const f4*)&e_in[gid*4];
    f4 sc = *(const f4*)&outs[n0];
    f4 sh = *(const f4*)&outs[128 + n0];
    f4 y;
    y.x = fmaxf(x.x*sc.x + sh.x, 0.f) + ei.x;
    y.y = fmaxf(x.y*sc.y + sh.y, 0.f) + ei.y;
    y.z = fmaxf(x.z*sc.z + sh.z, 0.f) + ei.z;
    y.w = fmaxf(x.w*sc.w + sh.w, 0.f) + ei.w;
    *(f4*)&eio[gid*4] = y;
}

// ---------------------------------------------------------------------------
extern "C" void kernel_launch(void* const* d_in, const int* in_sizes, int n_in,
                              void* d_out, int out_size, void* d_ws, size_t ws_size,
                              hipStream_t stream)
{
    (void)in_sizes; (void)n_in; (void)out_size; (void)ws_size;
    const float* h   = (const float*)d_in[0];
    const float* e   = (const float*)d_in[1];
    const int*   A   = (const int*)d_in[2];
    const int*   S   = (const int*)d_in[3];
    const float* WU  = (const float*)d_in[4];   const float* bU = (const float*)d_in[5];
    const float* WV  = (const float*)d_in[6];   const float* bV = (const float*)d_in[7];
    const float* WA_ = (const float*)d_in[8];   const float* bA = (const float*)d_in[9];
    const float* WB_ = (const float*)d_in[10];  const float* bB = (const float*)d_in[11];
    const float* WC_ = (const float*)d_in[12];  const float* bC = (const float*)d_in[13];
    const float* gamma_h = (const float*)d_in[14]; const float* beta_h = (const float*)d_in[15];
    const float* gamma_e = (const float*)d_in[16]; const float* beta_e = (const float*)d_in[17];

    float* ws    = (float*)d_ws;
    float* Uh    = ws;              // 1024*128
    float* Vh    = ws + 131072;
    float* Ahw   = ws + 262144;
    float* Bhw   = ws + 393216;
    float* aggS  = ws + 524288;
    float* aggA  = ws + 655360;
    float* h_new = ws + 786432;
    float* WCt   = ws + 917504;     // 128*128
    float* sums  = ws + 933888;     // 512: e_sum, e_ssq, h_sum, h_ssq
    float* outs  = ws + 934400;     // 512: e_scale, e_shift, h_scale, h_shift

    float* hout = (float*)d_out;
    float* eout = (float*)d_out + NROWS*HH;     // e_new then e_out, in place

    hipMemsetAsync(sums, 0, 512*sizeof(float), stream);
    hipMemsetAsync(aggS, 0, 262144*sizeof(float), stream);  // aggS+aggA (contig)
    k_linear4 <<<256,   256, 0, stream>>>(h, WU,bU, WV,bV, WA_,bA, WB_,bB, Uh);
    k_transpose<<<16,   256, 0, stream>>>(WC_, WCt);
    k_edge    <<<2048,  256, 0, stream>>>(e, A, S, WCt, bC, Ahw, Bhw, Vh,
                                          eout, aggS, aggA, sums);
    k_hnew    <<<128,   256, 0, stream>>>(Uh, aggS, aggA, h_new, sums);
    k_stats   <<<1,     128, 0, stream>>>(sums, outs, gamma_e, beta_e, gamma_h, beta_h);
    k_hout    <<<128,   256, 0, stream>>>(h, h_new, outs, hout);
    k_eout    <<<32768, 256, 0, stream>>>(e, outs, eout);
}